// Round 3
// baseline (395.678 us; speedup 1.0000x reference)
//
#include <hip/hip_runtime.h>
#include <hip/hip_bf16.h>
#include <stdint.h>

#define NN 50000
#define NE 800000
#define HID 128
#define NT_TILES 12500       // NE / 64
#define GRID_PERSIST 512     // 2 blocks/CU * 256 CUs
#define ROWD 68              // x1 row pitch in dwords (17 mod 32 -> conflict-free b128)

typedef float f32x4 __attribute__((ext_vector_type(4)));
typedef short s16x8 __attribute__((ext_vector_type(8)));
typedef unsigned int u32;

__device__ __forceinline__ unsigned short f2bf(float x) {   // RNE (prep only)
    u32 u = __float_as_uint(x);
    u32 r = (u + 0x7FFFu + ((u >> 16) & 1u)) >> 16;
    return (unsigned short)r;
}
// silu without IEEE divide
__device__ __forceinline__ float silu_f(float v) {
    float e = __expf(-v);
    return v * __builtin_amdgcn_rcpf(1.f + e);
}
// pack two f32 -> one dword of (bf16(lo) | bf16(hi)<<16), truncation
__device__ __forceinline__ u32 pack2bf(float lo, float hi) {
    return __builtin_amdgcn_perm(__float_as_uint(hi), __float_as_uint(lo), 0x07060302u);
}
__device__ __forceinline__ void async16(const void* g, void* l) {
    __builtin_amdgcn_global_load_lds(
        (const __attribute__((address_space(1))) u32*)g,
        (__attribute__((address_space(3))) u32*)l, 16, 0, 0);
}

// prep: W1 [257,128] -> W1p bf16 [32 kblk][128 n][8 kin] (K=256 only; row 256 handled in-kernel),
//       W2 [128,128] -> W2p bf16 [16 kblk][128 n][8 kin] with sigma k-permutation,
//       h f32 -> hb bf16 (RNE).
// sigma(p): t=p>>1 -> source row = 32*(t>>4) + (t&15) + 16*(p&1)  (matches x1 paired-store layout)
__global__ void prep_kernel(const float* __restrict__ W1, const float* __restrict__ W2,
                            const float* __restrict__ h,
                            unsigned short* __restrict__ W1p, unsigned short* __restrict__ W2p,
                            unsigned short* __restrict__ hb) {
    int idx = blockIdx.x * blockDim.x + threadIdx.x;
    const int n1 = 32 * 128 * 8;
    const int n2 = 16 * 128 * 8;
    if (idx < n1) {
        int kblk = idx >> 10;
        int rem  = idx & 1023;
        int n    = rem >> 3;
        int kin  = rem & 7;
        int k    = kblk * 8 + kin;
        W1p[idx] = f2bf(W1[k * HID + n]);
    } else if (idx < n1 + n2) {
        int jj   = idx - n1;
        int kblk = jj >> 10;
        int rem  = jj & 1023;
        int n    = rem >> 3;
        int kin  = rem & 7;
        int p    = kblk * 8 + kin;
        int tt   = p >> 1;
        int srow = 32 * (tt >> 4) + (tt & 15) + 16 * (p & 1);
        W2p[jj] = f2bf(W2[srow * HID + n]);
    } else {
        int j = idx - (n1 + n2);
        if (j < NN * HID / 4) {
            const float4 v = *(const float4*)(h + (size_t)j * 4);
            short4 pk;
            pk.x = (short)f2bf(v.x); pk.y = (short)f2bf(v.y);
            pk.z = (short)f2bf(v.z); pk.w = (short)f2bf(v.w);
            *(short4*)(hb + (size_t)j * 4) = pk;
        }
    }
}

__global__ __launch_bounds__(512, 4) void edge_kernel(
        const unsigned short* __restrict__ hb,
        const int* __restrict__ edge_index,
        const float* __restrict__ coord_diff,
        const float* __restrict__ edge_attr,
        const float* __restrict__ edge_mask,
        const unsigned short* __restrict__ W1p,
        const unsigned short* __restrict__ W2p,
        const float* __restrict__ W1,
        const float* __restrict__ b1,
        const float* __restrict__ b2,
        const float* __restrict__ W3,
        float* __restrict__ agg) {
    // s_inp: 64 edges x 256 bf16 (h[row]|h[col]), chunk-XOR-swizzled per row -> 32768 B
    __shared__ unsigned short s_inp[64 * 256];
    __shared__ u32   s_x1[64 * ROWD];            // 17408 B, sigma-paired bf16 layout
    __shared__ float s_phi[64 * 4];
    __shared__ float s_ea[64];

    const int tid  = threadIdx.x;
    const int w    = tid >> 6;
    const int lane = tid & 63;
    const int wm   = w >> 2;           // row half: rows [wm*32, wm*32+32)
    const int wn   = w & 3;            // col group: cols [wn*32, wn*32+32)
    const int q    = lane >> 4;
    const int c16  = lane & 15;
    const int n0   = wn * 32 + c16;
    const int rowbase = wm * 32;

    // persistent layer-1 B fragments: 8 ks x 2 nt = 64 VGPR
    s16x8 W1B[8][2];
    #pragma unroll
    for (int ks = 0; ks < 8; ++ks) {
        int kblk = ks * 4 + q;
        W1B[ks][0] = *(const s16x8*)(W1p + (size_t)(kblk * HID + n0) * 8);
        W1B[ks][1] = *(const s16x8*)(W1p + (size_t)(kblk * HID + n0 + 16) * 8);
    }
    const float b1v0 = b1[n0],           b1v1 = b1[n0 + 16];
    const float b2v0 = b2[n0],           b2v1 = b2[n0 + 16];
    const float w3v0 = W3[n0],           w3v1 = W3[n0 + 16];
    const float w1r0 = W1[256 * HID + n0], w1r1 = W1[256 * HID + n0 + 16];

    // staging lane constants: wave covers rows [w*8, w*8+8), 2 rows per async iter
    const int st_rsub  = lane >> 5;      // 0/1: which of the 2 rows
    const int st_j     = lane & 31;      // 16B chunk slot within 512B row
    const int st_which = st_j >> 4;      // 0: h[row], 1: h[col]
    const int st_j4    = st_j & 15;

    int t = blockIdx.x;
    {   // prologue: stage first tile
        int e0 = t * 64;
        int idxs[4];
        #pragma unroll
        for (int it = 0; it < 4; ++it) {
            int row = w * 8 + it * 2 + st_rsub;
            idxs[it] = edge_index[st_which * NE + e0 + row];
        }
        #pragma unroll
        for (int it = 0; it < 4; ++it) {
            int row0 = w * 8 + it * 2;
            int row  = row0 + st_rsub;
            int cg   = st_j4 ^ (row & 7);                 // XOR swizzle (global side)
            async16(hb + (size_t)idxs[it] * HID + cg * 8, &s_inp[row0 * 256]);
        }
        if (tid < 64) s_ea[tid] = edge_attr[e0 + tid];
    }

    for (; t < NT_TILES; t += GRID_PERSIST) {
        const int e0 = t * 64;
        __syncthreads();   // B1: tile t staging visible (each wave drained own vmcnt at prior barrier)

        // ---- layer 1: K=256, fragments from swizzled s_inp, persistent W1B ----
        f32x4 acc[2][2];
        #pragma unroll
        for (int mt = 0; mt < 2; ++mt) {
            acc[mt][0] = f32x4{0.f, 0.f, 0.f, 0.f};
            acc[mt][1] = f32x4{0.f, 0.f, 0.f, 0.f};
        }
        #pragma unroll
        for (int ks = 0; ks < 8; ++ks) {
            #pragma unroll
            for (int mt = 0; mt < 2; ++mt) {
                int m = rowbase + mt * 16 + c16;
                int c = ks * 4 + q;
                int slot = (c & 16) | ((c & 15) ^ (m & 7));   // un-swizzle
                s16x8 afr = *(const s16x8*)&s_inp[m * 256 + slot * 8];
                acc[mt][0] = __builtin_amdgcn_mfma_f32_16x16x32_bf16(afr, W1B[ks][0], acc[mt][0], 0, 0, 0);
                acc[mt][1] = __builtin_amdgcn_mfma_f32_16x16x32_bf16(afr, W1B[ks][1], acc[mt][1], 0, 0, 0);
            }
        }
        // edge_attr rank-1 correction (f32) + bias + silu + sigma-paired x1 store
        #pragma unroll
        for (int mt = 0; mt < 2; ++mt) {
            #pragma unroll
            for (int r = 0; r < 4; ++r) {
                int m = rowbase + mt * 16 + q * 4 + r;
                float ea = s_ea[m];
                float s0 = silu_f(acc[mt][0][r] + b1v0 + ea * w1r0);
                float s1 = silu_f(acc[mt][1][r] + b1v1 + ea * w1r1);
                s_x1[m * ROWD + wn * 16 + c16] = pack2bf(s0, s1);
            }
        }
        __syncthreads();   // B2: x1 ready; all s_inp reads done -> safe to restage

        // ---- stage tile t+GRID into s_inp (drains at B3, consumed after next B1) ----
        int tn = t + GRID_PERSIST;
        if (tn < NT_TILES) {
            int e0n = tn * 64;
            int idxs[4];
            #pragma unroll
            for (int it = 0; it < 4; ++it) {
                int row = w * 8 + it * 2 + st_rsub;
                idxs[it] = edge_index[st_which * NE + e0n + row];
            }
            #pragma unroll
            for (int it = 0; it < 4; ++it) {
                int row0 = w * 8 + it * 2;
                int row  = row0 + st_rsub;
                int cg   = st_j4 ^ (row & 7);
                async16(hb + (size_t)idxs[it] * HID + cg * 8, &s_inp[row0 * 256]);
            }
            if (tid < 64) s_ea[tid] = edge_attr[e0n + tid];
        }
        // epilogue data prefetch for current tile
        float cdx = 0.f, cdy = 0.f, cdz = 0.f, emv = 0.f; int ridx = 0;
        if (tid < 64) {
            int e = e0 + tid;
            cdx = coord_diff[e * 3 + 0];
            cdy = coord_diff[e * 3 + 1];
            cdz = coord_diff[e * 3 + 2];
            emv = edge_mask[e];
            ridx = edge_index[e];          // segment id = edge_index[0][e]
        }

        // ---- layer 2: x1 @ W2p (sigma-permuted K), 2-deep B pipeline ----
        f32x4 acc2[2][2];
        #pragma unroll
        for (int mt = 0; mt < 2; ++mt) {
            acc2[mt][0] = f32x4{0.f, 0.f, 0.f, 0.f};
            acc2[mt][1] = f32x4{0.f, 0.f, 0.f, 0.f};
        }
        s16x8 bcur0 = *(const s16x8*)(W2p + (size_t)(q * HID + n0) * 8);
        s16x8 bcur1 = *(const s16x8*)(W2p + (size_t)(q * HID + n0 + 16) * 8);
        #pragma unroll
        for (int ks = 0; ks < 4; ++ks) {
            s16x8 bn0, bn1;
            if (ks < 3) {
                int kblk = (ks + 1) * 4 + q;
                bn0 = *(const s16x8*)(W2p + (size_t)(kblk * HID + n0) * 8);
                bn1 = *(const s16x8*)(W2p + (size_t)(kblk * HID + n0 + 16) * 8);
            }
            #pragma unroll
            for (int mt = 0; mt < 2; ++mt) {
                int m = rowbase + mt * 16 + c16;
                s16x8 afr = *(const s16x8*)&s_x1[m * ROWD + ks * 16 + q * 4];
                acc2[mt][0] = __builtin_amdgcn_mfma_f32_16x16x32_bf16(afr, bcur0, acc2[mt][0], 0, 0, 0);
                acc2[mt][1] = __builtin_amdgcn_mfma_f32_16x16x32_bf16(afr, bcur1, acc2[mt][1], 0, 0, 0);
            }
            if (ks < 3) { bcur0 = bn0; bcur1 = bn1; }
        }

        // ---- layer 3: phi = sum_n silu(x2+b2)*W3, reduce over 16 cols, cross-wn via LDS ----
        #pragma unroll
        for (int mt = 0; mt < 2; ++mt) {
            float pr[4];
            #pragma unroll
            for (int r = 0; r < 4; ++r) {
                float s0 = silu_f(acc2[mt][0][r] + b2v0);
                float s1 = silu_f(acc2[mt][1][r] + b2v1);
                pr[r] = s0 * w3v0 + s1 * w3v1;
            }
            #pragma unroll
            for (int off = 8; off >= 1; off >>= 1) {
                #pragma unroll
                for (int r = 0; r < 4; ++r) pr[r] += __shfl_xor(pr[r], off);
            }
            if (c16 == 0) {
                #pragma unroll
                for (int r = 0; r < 4; ++r)
                    s_phi[(rowbase + mt * 16 + q * 4 + r) * 4 + wn] = pr[r];
            }
        }
        __syncthreads();   // B3: phi ready; also drains this wave's staged async loads

        if (tid < 64) {
            float phi = s_phi[tid * 4 + 0] + s_phi[tid * 4 + 1]
                      + s_phi[tid * 4 + 2] + s_phi[tid * 4 + 3];
            float scale = phi * emv;
            atomicAdd(&agg[ridx * 3 + 0], cdx * scale);
            atomicAdd(&agg[ridx * 3 + 1], cdy * scale);
            atomicAdd(&agg[ridx * 3 + 2], cdz * scale);
        }
    }
}

__global__ void finalize_kernel(const float* __restrict__ coord,
                                const float* __restrict__ node_mask,
                                float* __restrict__ out) {
    int i = blockIdx.x * blockDim.x + threadIdx.x;
    if (i < NN) {
        float nm = node_mask[i];
        float a0 = out[i * 3 + 0], a1 = out[i * 3 + 1], a2 = out[i * 3 + 2];
        out[i * 3 + 0] = (coord[i * 3 + 0] + a0 * 0.01f) * nm;
        out[i * 3 + 1] = (coord[i * 3 + 1] + a1 * 0.01f) * nm;
        out[i * 3 + 2] = (coord[i * 3 + 2] + a2 * 0.01f) * nm;
    }
}

extern "C" void kernel_launch(void* const* d_in, const int* in_sizes, int n_in,
                              void* d_out, int out_size, void* d_ws, size_t ws_size,
                              hipStream_t stream) {
    const float* h          = (const float*)d_in[0];
    const float* coord      = (const float*)d_in[1];
    const int*   edge_index = (const int*)d_in[2];
    const float* coord_diff = (const float*)d_in[3];
    // d_in[4] coord_cross: unused by the reference
    const float* edge_attr  = (const float*)d_in[5];
    const float* node_mask  = (const float*)d_in[6];
    const float* edge_mask  = (const float*)d_in[7];
    const float* W1         = (const float*)d_in[8];
    const float* b1         = (const float*)d_in[9];
    const float* W2         = (const float*)d_in[10];
    const float* b2         = (const float*)d_in[11];
    const float* W3         = (const float*)d_in[12];
    float* out = (float*)d_out;

    const int n1 = 32 * 128 * 8;   // W1p shorts (64 KB)
    const int n2 = 16 * 128 * 8;   // W2p shorts (32 KB)
    unsigned short* W1p = (unsigned short*)d_ws;
    unsigned short* W2p = W1p + n1;
    unsigned short* hb  = W2p + n2;      // 12.8 MB bf16 h (ws_size verified sufficient in R2)

    // agg accumulates directly in d_out
    hipMemsetAsync(d_out, 0, (size_t)out_size * sizeof(float), stream);

    int prep_items = n1 + n2 + NN * HID / 4;
    prep_kernel<<<(prep_items + 255) / 256, 256, 0, stream>>>(W1, W2, h, W1p, W2p, hb);

    edge_kernel<<<GRID_PERSIST, 512, 0, stream>>>(hb, edge_index, coord_diff, edge_attr,
                                                  edge_mask, W1p, W2p, W1, b1, b2, W3, out);

    finalize_kernel<<<(NN + 255) / 256, 256, 0, stream>>>(coord, node_mask, out);
}

// Round 4
// 263.098 us; speedup vs baseline: 1.5039x; 1.5039x over previous
//
#include <hip/hip_runtime.h>
#include <hip/hip_bf16.h>

#define NN 50000
#define NE 800000
#define HID 128
#define ROWD 68           // x1 LDS pitch in dwords (68%32=4 -> ~2-way banks)
#define APITCH 136        // node-gemm A-tile pitch in bf16 elems (=68 dwords)

typedef float f32x4 __attribute__((ext_vector_type(4)));
typedef short s16x8 __attribute__((ext_vector_type(8)));
typedef unsigned int u32;

__device__ __forceinline__ unsigned short f2bf(float x) {   // RNE
    u32 u = __float_as_uint(x);
    u32 r = (u + 0x7FFFu + ((u >> 16) & 1u)) >> 16;
    return (unsigned short)r;
}
__device__ __forceinline__ float silu_f(float v) {          // no IEEE divide
    float e = __expf(-v);
    return v * __builtin_amdgcn_rcpf(1.f + e);
}
// pack two f32 -> dword (bf16 lo | bf16 hi<<16), truncation
__device__ __forceinline__ u32 pack2bf(float lo, float hi) {
    return __builtin_amdgcn_perm(__float_as_uint(hi), __float_as_uint(lo), 0x07060302u);
}

// ============================ FULL PATH ============================
// prep: W1 rows 0..255 -> W1p bf16 [32 kblk][128 n][8 kin]
//       W2 -> W2p bf16 [16 kblk][128 n][8 kin], sigma k-permutation matching
//       the x1 paired LDS layout (verified in R3):
//       p=kblk*8+kin, t=p>>1, srow = 32*(t>>4) + (t&15) + 16*(p&1)
__global__ void prep_full(const float* __restrict__ W1, const float* __restrict__ W2,
                          unsigned short* __restrict__ W1p, unsigned short* __restrict__ W2p) {
    int idx = blockIdx.x * blockDim.x + threadIdx.x;
    const int n1 = 32 * 128 * 8;
    const int n2 = 16 * 128 * 8;
    if (idx < n1) {
        int kblk = idx >> 10;
        int rem  = idx & 1023;
        int n    = rem >> 3;
        int kin  = rem & 7;
        W1p[idx] = f2bf(W1[(kblk * 8 + kin) * HID + n]);
    } else if (idx < n1 + n2) {
        int jj   = idx - n1;
        int kblk = jj >> 10;
        int rem  = jj & 1023;
        int n    = rem >> 3;
        int kin  = rem & 7;
        int p    = kblk * 8 + kin;
        int tt   = p >> 1;
        int srow = 32 * (tt >> 4) + (tt & 15) + 16 * (p & 1);
        W2p[jj] = f2bf(W2[srow * HID + n]);
    }
}

// node_gemm: Pa[n] = h[n] @ W1[0:128,:] + b1  (stored sigma-paired bf16, 64 dwords/row)
//            Pb[n] = h[n] @ W1[128:256,:]
// dword d of a row holds cols (32*(d>>4)+(d&15), +16) as (lo,hi) bf16.
__global__ __launch_bounds__(256) void node_gemm(const float* __restrict__ h,
                                                 const unsigned short* __restrict__ W1p,
                                                 const float* __restrict__ b1,
                                                 u32* __restrict__ Pa, u32* __restrict__ Pb) {
    __shared__ unsigned short s_a[64 * APITCH];   // 17408 B
    const int tid = threadIdx.x;
    const int m0  = blockIdx.x * 64;

    // stage 64 rows x 128 f32 -> bf16 LDS (RNE)
    #pragma unroll
    for (int it = 0; it < 8; ++it) {
        int chunk = it * 256 + tid;       // 0..2047 float4 chunks
        int r  = chunk >> 5;
        int cc = chunk & 31;
        int row = m0 + r;
        float4 v = {0.f, 0.f, 0.f, 0.f};
        if (row < NN) v = *(const float4*)(h + (size_t)row * HID + cc * 4);
        uint2 pk;
        pk.x = ((u32)f2bf(v.x)) | ((u32)f2bf(v.y) << 16);
        pk.y = ((u32)f2bf(v.z)) | ((u32)f2bf(v.w) << 16);
        *(uint2*)&s_a[r * APITCH + cc * 4] = pk;
    }
    __syncthreads();

    const int lane = tid & 63;
    const int w    = tid >> 6;
    const int q    = lane >> 4;
    const int c16  = lane & 15;
    const int n0   = w * 32 + c16;

    f32x4 accA[4][2], accB[4][2];
    #pragma unroll
    for (int mt = 0; mt < 4; ++mt) {
        accA[mt][0] = f32x4{0.f,0.f,0.f,0.f}; accA[mt][1] = f32x4{0.f,0.f,0.f,0.f};
        accB[mt][0] = f32x4{0.f,0.f,0.f,0.f}; accB[mt][1] = f32x4{0.f,0.f,0.f,0.f};
    }
    #pragma unroll
    for (int ks = 0; ks < 4; ++ks) {
        s16x8 afr[4];
        #pragma unroll
        for (int mt = 0; mt < 4; ++mt)
            afr[mt] = *(const s16x8*)&s_a[(mt * 16 + c16) * APITCH + ks * 32 + q * 8];
        int ka = ks * 4 + q;          // Pa: W1 k rows 0..127
        int kb = 16 + ks * 4 + q;     // Pb: W1 k rows 128..255
        s16x8 ba0 = *(const s16x8*)(W1p + (size_t)(ka * HID + n0) * 8);
        s16x8 ba1 = *(const s16x8*)(W1p + (size_t)(ka * HID + n0 + 16) * 8);
        s16x8 bb0 = *(const s16x8*)(W1p + (size_t)(kb * HID + n0) * 8);
        s16x8 bb1 = *(const s16x8*)(W1p + (size_t)(kb * HID + n0 + 16) * 8);
        #pragma unroll
        for (int mt = 0; mt < 4; ++mt) {
            accA[mt][0] = __builtin_amdgcn_mfma_f32_16x16x32_bf16(afr[mt], ba0, accA[mt][0], 0, 0, 0);
            accA[mt][1] = __builtin_amdgcn_mfma_f32_16x16x32_bf16(afr[mt], ba1, accA[mt][1], 0, 0, 0);
            accB[mt][0] = __builtin_amdgcn_mfma_f32_16x16x32_bf16(afr[mt], bb0, accB[mt][0], 0, 0, 0);
            accB[mt][1] = __builtin_amdgcn_mfma_f32_16x16x32_bf16(afr[mt], bb1, accB[mt][1], 0, 0, 0);
        }
    }
    // epilogue: sigma-paired store; fold b1 into Pa
    float b1lo = b1[n0], b1hi = b1[n0 + 16];
    const int d = w * 16 + c16;
    #pragma unroll
    for (int mt = 0; mt < 4; ++mt) {
        #pragma unroll
        for (int r = 0; r < 4; ++r) {
            int m = mt * 16 + q * 4 + r;       // C/D: col=lane&15, row=quad*4+reg
            int row = m0 + m;
            if (row < NN) {
                Pa[(size_t)row * 64 + d] = pack2bf(accA[mt][0][r] + b1lo, accA[mt][1][r] + b1hi);
                Pb[(size_t)row * 64 + d] = pack2bf(accB[mt][0][r], accB[mt][1][r]);
            }
        }
    }
}

__device__ __forceinline__ u32 fuse_silu_pack(u32 a, u32 b, float ea, float wlo, float whi) {
    float xlo = __uint_as_float(a << 16) + __uint_as_float(b << 16) + ea * wlo;
    float xhi = __uint_as_float(a & 0xFFFF0000u) + __uint_as_float(b & 0xFFFF0000u) + ea * whi;
    return pack2bf(silu_f(xlo), silu_f(xhi));
}

__global__ __launch_bounds__(256) void edge_main(
        const u32* __restrict__ Pa, const u32* __restrict__ Pb,
        const int* __restrict__ edge_index,
        const float* __restrict__ coord_diff, const float* __restrict__ edge_attr,
        const float* __restrict__ edge_mask,
        const unsigned short* __restrict__ W2p,
        const float* __restrict__ W1, const float* __restrict__ b2,
        const float* __restrict__ W3, float* __restrict__ agg) {
    __shared__ u32   s_x1[64 * ROWD];   // 17408 B, sigma-paired bf16
    __shared__ float s_phi[64 * 4];
    __shared__ float s_ea[64];
    __shared__ int   s_idx[128];        // [m][0]=row, [m][1]=col

    const int tid = threadIdx.x;
    const int e0  = blockIdx.x * 64;

    if (tid < 128) s_idx[tid] = edge_index[(tid & 1) * NE + e0 + (tid >> 1)];
    else if (tid < 192) s_ea[tid - 128] = edge_attr[e0 + tid - 128];

    // per-thread W1-row-256 constants in sigma order (c = dword group)
    const int c = tid & 15;
    float w1rlo[4], w1rhi[4];
    #pragma unroll
    for (int i = 0; i < 4; ++i) {
        int d  = c * 4 + i;
        int cl = 32 * (d >> 4) + (d & 15);
        w1rlo[i] = W1[256 * HID + cl];
        w1rhi[i] = W1[256 * HID + cl + 16];
    }
    __syncthreads();

    // gather Pa[row]+Pb[col], fuse ea*w1r + silu, write x1 tile
    #pragma unroll
    for (int it = 0; it < 4; ++it) {
        int m  = it * 16 + (tid >> 4);
        int ri = s_idx[2 * m];
        int ci = s_idx[2 * m + 1];
        float ea = s_ea[m];
        uint4 pa = *(const uint4*)(Pa + (size_t)ri * 64 + c * 4);
        uint4 pb = *(const uint4*)(Pb + (size_t)ci * 64 + c * 4);
        uint4 o;
        o.x = fuse_silu_pack(pa.x, pb.x, ea, w1rlo[0], w1rhi[0]);
        o.y = fuse_silu_pack(pa.y, pb.y, ea, w1rlo[1], w1rhi[1]);
        o.z = fuse_silu_pack(pa.z, pb.z, ea, w1rlo[2], w1rhi[2]);
        o.w = fuse_silu_pack(pa.w, pb.w, ea, w1rlo[3], w1rhi[3]);
        *(uint4*)&s_x1[m * ROWD + c * 4] = o;
    }
    __syncthreads();

    const int lane = tid & 63;
    const int w    = tid >> 6;
    const int q    = lane >> 4;
    const int c16  = lane & 15;
    const int n0   = w * 32 + c16;

    // layer 2: [64,128] @ W2p (sigma-permuted K)
    f32x4 acc2[4][2];
    #pragma unroll
    for (int mt = 0; mt < 4; ++mt) {
        acc2[mt][0] = f32x4{0.f,0.f,0.f,0.f};
        acc2[mt][1] = f32x4{0.f,0.f,0.f,0.f};
    }
    #pragma unroll
    for (int ks = 0; ks < 4; ++ks) {
        int kblk = ks * 4 + q;
        s16x8 b0 = *(const s16x8*)(W2p + (size_t)(kblk * HID + n0) * 8);
        s16x8 b1f = *(const s16x8*)(W2p + (size_t)(kblk * HID + n0 + 16) * 8);
        #pragma unroll
        for (int mt = 0; mt < 4; ++mt) {
            s16x8 afr = *(const s16x8*)&s_x1[(mt * 16 + c16) * ROWD + ks * 16 + q * 4];
            acc2[mt][0] = __builtin_amdgcn_mfma_f32_16x16x32_bf16(afr, b0, acc2[mt][0], 0, 0, 0);
            acc2[mt][1] = __builtin_amdgcn_mfma_f32_16x16x32_bf16(afr, b1f, acc2[mt][1], 0, 0, 0);
        }
    }

    // layer 3: phi = sum_n silu(x2+b2)*W3
    {
        float b2lo = b2[n0], b2hi = b2[n0 + 16];
        float w3lo = W3[n0], w3hi = W3[n0 + 16];
        #pragma unroll
        for (int mt = 0; mt < 4; ++mt) {
            float pr[4];
            #pragma unroll
            for (int r = 0; r < 4; ++r) {
                float s0 = silu_f(acc2[mt][0][r] + b2lo);
                float s1 = silu_f(acc2[mt][1][r] + b2hi);
                pr[r] = s0 * w3lo + s1 * w3hi;
            }
            #pragma unroll
            for (int off = 8; off >= 1; off >>= 1) {
                #pragma unroll
                for (int r = 0; r < 4; ++r) pr[r] += __shfl_xor(pr[r], off);
            }
            if (c16 == 0) {
                #pragma unroll
                for (int r = 0; r < 4; ++r)
                    s_phi[(mt * 16 + q * 4 + r) * 4 + w] = pr[r];
            }
        }
    }
    __syncthreads();

    if (tid < 64) {
        int e = e0 + tid;
        float phi = s_phi[tid * 4 + 0] + s_phi[tid * 4 + 1]
                  + s_phi[tid * 4 + 2] + s_phi[tid * 4 + 3];
        float scale = phi * edge_mask[e];
        int r = s_idx[tid << 1];
        atomicAdd(&agg[r * 3 + 0], coord_diff[e * 3 + 0] * scale);
        atomicAdd(&agg[r * 3 + 1], coord_diff[e * 3 + 1] * scale);
        atomicAdd(&agg[r * 3 + 2], coord_diff[e * 3 + 2] * scale);
    }
}

// ============================ R2 FALLBACK (ws too small) ============================
#define P1R 296
#define P2R 152

__global__ void prep_r2(const float* __restrict__ W1, const float* __restrict__ W2,
                        const float* __restrict__ h,
                        unsigned short* __restrict__ W1p, unsigned short* __restrict__ W2p,
                        unsigned short* __restrict__ hb) {
    int idx = blockIdx.x * blockDim.x + threadIdx.x;
    const int n1 = 36 * 128 * 8;
    const int n2 = 16 * 128 * 8;
    if (idx < n1) {
        int kblk = idx >> 10; int rem = idx & 1023; int n = rem >> 3; int kin = rem & 7;
        int k = kblk * 8 + kin;
        W1p[idx] = (k < 257) ? f2bf(W1[k * HID + n]) : 0;
    } else if (idx < n1 + n2) {
        int j = idx - n1;
        int kblk = j >> 10; int rem = j & 1023; int n = rem >> 3; int kin = rem & 7;
        W2p[j] = f2bf(W2[(kblk * 8 + kin) * HID + n]);
    } else {
        int j = idx - (n1 + n2);
        if (j < NN * HID / 4) {
            const float4 v = *(const float4*)(h + (size_t)j * 4);
            short4 pk;
            pk.x = (short)f2bf(v.x); pk.y = (short)f2bf(v.y);
            pk.z = (short)f2bf(v.z); pk.w = (short)f2bf(v.w);
            *(short4*)(hb + (size_t)j * 4) = pk;
        }
    }
}

__global__ __launch_bounds__(256) void edge_r2(
        const unsigned short* __restrict__ hb, const int* __restrict__ edge_index,
        const float* __restrict__ coord_diff, const float* __restrict__ edge_attr,
        const float* __restrict__ edge_mask,
        const unsigned short* __restrict__ W1p, const unsigned short* __restrict__ W2p,
        const float* __restrict__ b1, const float* __restrict__ b2,
        const float* __restrict__ W3, float* __restrict__ agg) {
    __shared__ short s_inp[64 * P1R];
    __shared__ float s_phi[64 * 4];
    __shared__ int   s_idx[128];
    const int tid = threadIdx.x;
    const int e0  = blockIdx.x * 64;
    if (tid < 128) s_idx[tid] = edge_index[(tid & 1) * NE + e0 + (tid >> 1)];
    __syncthreads();
    #pragma unroll
    for (int it = 0; it < 8; ++it) {
        int cc = it * 256 + tid;
        int m = cc >> 5, sub = cc & 31, which = sub >> 4, part = sub & 15;
        int idx = s_idx[(m << 1) | which];
        s16x8 v = *(const s16x8*)(hb + (size_t)idx * HID + part * 8);
        *(s16x8*)&s_inp[m * P1R + which * HID + part * 8] = v;
    }
    if (tid < 64) {
        short4 z; z.x = z.y = z.z = z.w = 0;
        short* p = &s_inp[tid * P1R + 256];
        #pragma unroll
        for (int i = 0; i < 40; i += 4) *(short4*)(p + i) = z;
        p[0] = (short)f2bf(edge_attr[e0 + tid]);
    }
    __syncthreads();
    const int lane = tid & 63, w = tid >> 6, q = lane >> 4, c16 = lane & 15;
    const int n0 = w * 32 + c16;
    f32x4 acc[4][2];
    #pragma unroll
    for (int mt = 0; mt < 4; ++mt) { acc[mt][0] = f32x4{0,0,0,0}; acc[mt][1] = f32x4{0,0,0,0}; }
    #pragma unroll
    for (int ks = 0; ks < 9; ++ks) {
        int k0 = ks * 32, kblk = ks * 4 + q;
        s16x8 b0 = *(const s16x8*)(W1p + (size_t)(kblk * HID + n0) * 8);
        s16x8 bA = *(const s16x8*)(W1p + (size_t)(kblk * HID + n0 + 16) * 8);
        #pragma unroll
        for (int mt = 0; mt < 4; ++mt) {
            s16x8 afr = *(const s16x8*)&s_inp[(mt * 16 + c16) * P1R + k0 + q * 8];
            acc[mt][0] = __builtin_amdgcn_mfma_f32_16x16x32_bf16(afr, b0, acc[mt][0], 0, 0, 0);
            acc[mt][1] = __builtin_amdgcn_mfma_f32_16x16x32_bf16(afr, bA, acc[mt][1], 0, 0, 0);
        }
    }
    __syncthreads();
    {
        float b1v0 = b1[n0], b1v1 = b1[n0 + 16];
        #pragma unroll
        for (int mt = 0; mt < 4; ++mt)
            #pragma unroll
            for (int r = 0; r < 4; ++r) {
                int m = mt * 16 + q * 4 + r;
                float s0 = silu_f(acc[mt][0][r] + b1v0);
                float s1 = silu_f(acc[mt][1][r] + b1v1);
                s_inp[m * P2R + n0]      = (short)(__float_as_uint(s0) >> 16);
                s_inp[m * P2R + n0 + 16] = (short)(__float_as_uint(s1) >> 16);
            }
    }
    __syncthreads();
    f32x4 acc2[4][2];
    #pragma unroll
    for (int mt = 0; mt < 4; ++mt) { acc2[mt][0] = f32x4{0,0,0,0}; acc2[mt][1] = f32x4{0,0,0,0}; }
    #pragma unroll
    for (int ks = 0; ks < 4; ++ks) {
        int k0 = ks * 32, kblk = ks * 4 + q;
        s16x8 b0 = *(const s16x8*)(W2p + (size_t)(kblk * HID + n0) * 8);
        s16x8 bA = *(const s16x8*)(W2p + (size_t)(kblk * HID + n0 + 16) * 8);
        #pragma unroll
        for (int mt = 0; mt < 4; ++mt) {
            s16x8 afr = *(const s16x8*)&s_inp[(mt * 16 + c16) * P2R + k0 + q * 8];
            acc2[mt][0] = __builtin_amdgcn_mfma_f32_16x16x32_bf16(afr, b0, acc2[mt][0], 0, 0, 0);
            acc2[mt][1] = __builtin_amdgcn_mfma_f32_16x16x32_bf16(afr, bA, acc2[mt][1], 0, 0, 0);
        }
    }
    {
        float b2v0 = b2[n0], b2v1 = b2[n0 + 16];
        float w30 = W3[n0], w31 = W3[n0 + 16];
        #pragma unroll
        for (int mt = 0; mt < 4; ++mt) {
            float pr[4];
            #pragma unroll
            for (int r = 0; r < 4; ++r) {
                float s0 = silu_f(acc2[mt][0][r] + b2v0);
                float s1 = silu_f(acc2[mt][1][r] + b2v1);
                pr[r] = s0 * w30 + s1 * w31;
            }
            #pragma unroll
            for (int off = 8; off >= 1; off >>= 1)
                #pragma unroll
                for (int r = 0; r < 4; ++r) pr[r] += __shfl_xor(pr[r], off);
            if (c16 == 0)
                #pragma unroll
                for (int r = 0; r < 4; ++r) s_phi[(mt * 16 + q * 4 + r) * 4 + w] = pr[r];
        }
    }
    __syncthreads();
    if (tid < 64) {
        int e = e0 + tid;
        float phi = s_phi[tid*4+0] + s_phi[tid*4+1] + s_phi[tid*4+2] + s_phi[tid*4+3];
        float scale = phi * edge_mask[e];
        int r = s_idx[tid << 1];
        atomicAdd(&agg[r * 3 + 0], coord_diff[e * 3 + 0] * scale);
        atomicAdd(&agg[r * 3 + 1], coord_diff[e * 3 + 1] * scale);
        atomicAdd(&agg[r * 3 + 2], coord_diff[e * 3 + 2] * scale);
    }
}

// ============================ shared epilogue ============================
__global__ void finalize_kernel(const float* __restrict__ coord,
                                const float* __restrict__ node_mask,
                                float* __restrict__ out) {
    int i = blockIdx.x * blockDim.x + threadIdx.x;
    if (i < NN) {
        float nm = node_mask[i];
        float a0 = out[i*3+0], a1 = out[i*3+1], a2 = out[i*3+2];
        out[i*3+0] = (coord[i*3+0] + a0 * 0.01f) * nm;
        out[i*3+1] = (coord[i*3+1] + a1 * 0.01f) * nm;
        out[i*3+2] = (coord[i*3+2] + a2 * 0.01f) * nm;
    }
}

extern "C" void kernel_launch(void* const* d_in, const int* in_sizes, int n_in,
                              void* d_out, int out_size, void* d_ws, size_t ws_size,
                              hipStream_t stream) {
    const float* h          = (const float*)d_in[0];
    const float* coord      = (const float*)d_in[1];
    const int*   edge_index = (const int*)d_in[2];
    const float* coord_diff = (const float*)d_in[3];
    const float* edge_attr  = (const float*)d_in[5];
    const float* node_mask  = (const float*)d_in[6];
    const float* edge_mask  = (const float*)d_in[7];
    const float* W1         = (const float*)d_in[8];
    const float* b1         = (const float*)d_in[9];
    const float* W2         = (const float*)d_in[10];
    const float* b2         = (const float*)d_in[11];
    const float* W3         = (const float*)d_in[12];
    float* out = (float*)d_out;

    hipMemsetAsync(d_out, 0, (size_t)out_size * sizeof(float), stream);

    const size_t nW1 = 32 * 128 * 8;   // shorts
    const size_t nW2 = 16 * 128 * 8;
    const size_t need_full = (nW1 + nW2) * 2 + 2 * (size_t)NN * 64 * 4;  // ~25.7 MB

    if (ws_size >= need_full) {
        unsigned short* W1p = (unsigned short*)d_ws;
        unsigned short* W2p = W1p + nW1;
        u32* Pa = (u32*)(W2p + nW2);
        u32* Pb = Pa + (size_t)NN * 64;

        int prep_items = (int)(nW1 + nW2);
        prep_full<<<(prep_items + 255) / 256, 256, 0, stream>>>(W1, W2, W1p, W2p);
        node_gemm<<<(NN + 63) / 64, 256, 0, stream>>>(h, W1p, b1, Pa, Pb);
        edge_main<<<NE / 64, 256, 0, stream>>>(Pa, Pb, edge_index, coord_diff, edge_attr,
                                               edge_mask, W2p, W1, b2, W3, out);
    } else {
        const int n1 = 36 * 128 * 8, n2 = 16 * 128 * 8;
        unsigned short* W1p = (unsigned short*)d_ws;
        unsigned short* W2p = W1p + n1;
        unsigned short* hb  = W2p + n2;
        int prep_items = n1 + n2 + NN * HID / 4;
        prep_r2<<<(prep_items + 255) / 256, 256, 0, stream>>>(W1, W2, h, W1p, W2p, hb);
        edge_r2<<<NE / 64, 256, 0, stream>>>(hb, edge_index, coord_diff, edge_attr, edge_mask,
                                             W1p, W2p, b1, b2, W3, out);
    }

    finalize_kernel<<<(NN + 255) / 256, 256, 0, stream>>>(coord, node_mask, out);
}